// Round 19
// baseline (774.741 us; speedup 1.0000x reference)
//
#include <hip/hip_runtime.h>
#include <hip/hip_bf16.h>
#include <stdint.h>

#define SLEN 2048
#define HIDN 4096
#define NHEAD 32
#define NKV 8
#define HD 128
#define QKV_N 6144

typedef __hip_bfloat16 bf16;
typedef short short8 __attribute__((ext_vector_type(8)));
typedef _Float16 f16x8 __attribute__((ext_vector_type(8)));
typedef float f32x4 __attribute__((ext_vector_type(4)));
typedef float f32x16 __attribute__((ext_vector_type(16)));

__device__ __forceinline__ void gld16(const void* g, void* l) {
  __builtin_amdgcn_global_load_lds((const __attribute__((address_space(1))) void*)g,
                                   (__attribute__((address_space(3))) void*)l,
                                   16, 0, 0);
}

// packed bf16 convert: lo16 = bf16(a), hi16 = bf16(b)  [T12 recipe]
__device__ __forceinline__ unsigned int cvtpk(float a, float b) {
  unsigned int r;
  asm("v_cvt_pk_bf16_f32 %0, %1, %2" : "=v"(r) : "v"(a), "v"(b));
  return r;
}

// Pipelined bf16 GEMM (round-12 proven): C[M,N](fp32) = A[M,K] * B[N,K]^T.
__global__ __launch_bounds__(256, 2) void gemm_pipe_kernel(
    const bf16* __restrict__ A, const bf16* __restrict__ B,
    float* __restrict__ C, int K, int lda, int ldb, int ldc)
{
  __shared__ __align__(16) bf16 sA[2][128 * 64];
  __shared__ __align__(16) bf16 sB[2][128 * 64];

  const int bidlin = blockIdx.y * gridDim.x + blockIdx.x;
  const int xcd = bidlin & 7;
  const int local = bidlin >> 3;
  const int CW = gridDim.x >> 2;
  const int cx = xcd & 3, cy = xcd >> 2;
  const int bx = cx * CW + local % CW;
  const int by = cy * (gridDim.y >> 1) + local / CW;
  const int row0 = by * 128;
  const int col0 = bx * 128;

  const int tid = threadIdx.x;
  const int w = tid >> 6;
  const int lane = tid & 63;
  const int wr = w >> 1, wc = w & 1;
  const int fr = lane & 15;
  const int g = lane >> 4;

  auto stage = [&](int t, int b) {
    const int k0 = t << 6;
#pragma unroll
    for (int i = 0; i < 4; ++i) {
      const int c = i * 256 + tid;
      const int row = c >> 3;
      const int slot = (c & 7) ^ (row & 7);
      gld16(A + (long)(row0 + row) * lda + k0 + slot * 8,
            (bf16*)sA[b] + (i * 256 + w * 64) * 8);
    }
#pragma unroll
    for (int i = 0; i < 4; ++i) {
      const int c = i * 256 + tid;
      const int row = c >> 3;
      const int slot = (c & 7) ^ (row & 7);
      gld16(B + (long)(col0 + row) * ldb + k0 + slot * 8,
            (bf16*)sB[b] + (i * 256 + w * 64) * 8);
    }
  };

  f32x4 acc[4][4] = {};
  const int nk = K >> 6;

  stage(0, 0);

  for (int t = 0; t < nk; ++t) {
    const int buf = t & 1;
    __builtin_amdgcn_s_barrier();
    __builtin_amdgcn_sched_barrier(0);
    if (t + 1 < nk) {
      stage(t + 1, buf ^ 1);
      asm volatile("s_waitcnt vmcnt(8)" ::: "memory");
    } else {
      asm volatile("s_waitcnt vmcnt(0)" ::: "memory");
    }
    __builtin_amdgcn_sched_barrier(0);
    __builtin_amdgcn_s_barrier();
    __builtin_amdgcn_sched_barrier(0);

    const bf16* Ab = sA[buf];
    const bf16* Bb = sB[buf];

    short8 afr[4][2], bfr[4][2];
#pragma unroll
    for (int mf = 0; mf < 4; ++mf)
#pragma unroll
      for (int ks = 0; ks < 2; ++ks) {
        const int ra = wr * 64 + mf * 16 + fr;
        afr[mf][ks] = *(const short8*)(Ab + ra * 64 + (((ks << 2) + g) ^ (ra & 7)) * 8);
        const int rb = wc * 64 + mf * 16 + fr;
        bfr[mf][ks] = *(const short8*)(Bb + rb * 64 + (((ks << 2) + g) ^ (rb & 7)) * 8);
      }
    __builtin_amdgcn_s_setprio(1);
#pragma unroll
    for (int mf = 0; mf < 4; ++mf)
#pragma unroll
      for (int nf = 0; nf < 4; ++nf)
#pragma unroll
        for (int ks = 0; ks < 2; ++ks)
          acc[mf][nf] = __builtin_amdgcn_mfma_f32_16x16x32_bf16(
              afr[mf][ks], bfr[nf][ks], acc[mf][nf], 0, 0, 0);
    __builtin_amdgcn_s_setprio(0);
  }

  const int cr = g << 2;
#pragma unroll
  for (int mf = 0; mf < 4; ++mf)
#pragma unroll
    for (int nf = 0; nf < 4; ++nf)
#pragma unroll
      for (int r = 0; r < 4; ++r) {
        const long row = row0 + wr * 64 + mf * 16 + cr + r;
        const long col = col0 + wc * 64 + nf * 16 + fr;
        C[row * (long)ldc + col] = acc[mf][nf][r];
      }
}

// QKV GEMM with fused epilogue (round-14 proven, reverted from the BK=32
// variant: its swizzle had a 12.6M-conflict bug and the bf16 RoPE partner
// cost accuracy margin for zero speed).
__global__ __launch_bounds__(256, 2) void gemm_qkv_kernel(
    const bf16* __restrict__ A, const bf16* __restrict__ B,
    _Float16* __restrict__ qf, _Float16* __restrict__ kf,
    bf16* __restrict__ Vt,
    const float* __restrict__ cosb, const float* __restrict__ sinb,
    const float* __restrict__ qw, const float* __restrict__ kw,
    const float* __restrict__ epsp, int K, int lda, int ldb)
{
  __shared__ __align__(16) char smem[128 * 133 * 4];
  bf16* sAb = (bf16*)smem;
  bf16* sBb = (bf16*)(smem + 32768);
  float* T = (float*)smem;

  const int bidlin = blockIdx.y * gridDim.x + blockIdx.x;
  const int xcd = bidlin & 7;
  const int local = bidlin >> 3;
  const int CW = gridDim.x >> 2;
  const int cx = xcd & 3, cy = xcd >> 2;
  const int bx = cx * CW + local % CW;
  const int by = cy * (gridDim.y >> 1) + local / CW;
  const int row0 = by * 128;
  const int col0 = bx * 128;

  const int tid = threadIdx.x;
  const int w = tid >> 6;
  const int lane = tid & 63;
  const int wr = w >> 1, wc = w & 1;
  const int fr = lane & 15;
  const int g = lane >> 4;

  auto stage = [&](int t, int b) {
    const int k0 = t << 6;
#pragma unroll
    for (int i = 0; i < 4; ++i) {
      const int c = i * 256 + tid;
      const int row = c >> 3;
      const int slot = (c & 7) ^ (row & 7);
      gld16(A + (long)(row0 + row) * lda + k0 + slot * 8,
            sAb + b * 8192 + (i * 256 + w * 64) * 8);
    }
#pragma unroll
    for (int i = 0; i < 4; ++i) {
      const int c = i * 256 + tid;
      const int row = c >> 3;
      const int slot = (c & 7) ^ (row & 7);
      gld16(B + (long)(col0 + row) * ldb + k0 + slot * 8,
            sBb + b * 8192 + (i * 256 + w * 64) * 8);
    }
  };

  f32x4 acc[4][4] = {};
  const int nk = K >> 6;

  stage(0, 0);

  for (int t = 0; t < nk; ++t) {
    const int buf = t & 1;
    __builtin_amdgcn_s_barrier();
    __builtin_amdgcn_sched_barrier(0);
    if (t + 1 < nk) {
      stage(t + 1, buf ^ 1);
      asm volatile("s_waitcnt vmcnt(8)" ::: "memory");
    } else {
      asm volatile("s_waitcnt vmcnt(0)" ::: "memory");
    }
    __builtin_amdgcn_sched_barrier(0);
    __builtin_amdgcn_s_barrier();
    __builtin_amdgcn_sched_barrier(0);

    const bf16* Ab = sAb + buf * 8192;
    const bf16* Bb = sBb + buf * 8192;

    short8 afr[4][2], bfr[4][2];
#pragma unroll
    for (int mf = 0; mf < 4; ++mf)
#pragma unroll
      for (int ks = 0; ks < 2; ++ks) {
        const int ra = wr * 64 + mf * 16 + fr;
        afr[mf][ks] = *(const short8*)(Ab + ra * 64 + (((ks << 2) + g) ^ (ra & 7)) * 8);
        const int rb = wc * 64 + mf * 16 + fr;
        bfr[mf][ks] = *(const short8*)(Bb + rb * 64 + (((ks << 2) + g) ^ (rb & 7)) * 8);
      }
    __builtin_amdgcn_s_setprio(1);
#pragma unroll
    for (int mf = 0; mf < 4; ++mf)
#pragma unroll
      for (int nf = 0; nf < 4; ++nf)
#pragma unroll
        for (int ks = 0; ks < 2; ++ks)
          acc[mf][nf] = __builtin_amdgcn_mfma_f32_16x16x32_bf16(
              afr[mf][ks], bfr[nf][ks], acc[mf][nf], 0, 0, 0);
    __builtin_amdgcn_s_setprio(0);
  }

  // ---- fused epilogue ----
  __syncthreads();
#pragma unroll
  for (int mf = 0; mf < 4; ++mf)
#pragma unroll
    for (int nf = 0; nf < 4; ++nf)
#pragma unroll
      for (int r = 0; r < 4; ++r)
        T[(wr * 64 + mf * 16 + (g << 2) + r) * 133 + wc * 64 + nf * 16 + fr] =
            acc[mf][nf][r];
  __syncthreads();

  const int slot = col0 >> 7;
  if (slot < 40) {
    const int rrow = w * 32 + (lane & 31);
    const int hi2 = lane >> 5;
    const long srow = row0 + rrow;
    const float* nw = (slot < 32) ? qw : kw;
    _Float16* dst;
    long base;
    float scale;
    if (slot < 32) {
      dst = qf; base = ((long)slot * SLEN + srow) * HD;
      scale = 1.4426950408889634f;
    } else {
      dst = kf; base = ((long)(slot - 32) * SLEN + srow) * HD;
      scale = 1.0f;
    }
    float ssq = 0.0f;
#pragma unroll
    for (int j = 0; j < 64; ++j) {
      const float v = T[rrow * 133 + hi2 * 64 + j];
      ssq += v * v;
    }
    ssq += __shfl_xor(ssq, 32);
    const float rr = rsqrtf(ssq * (1.0f / 128.0f) + epsp[0]);
#pragma unroll
    for (int jv = 0; jv < 8; ++jv) {
      f16x8 o8;
#pragma unroll
      for (int e = 0; e < 8; ++e) {
        const int d = hi2 * 64 + jv * 8 + e;
        const float nv  = T[rrow * 133 + d] * rr * nw[d];
        const float nvp = T[rrow * 133 + (d ^ 64)] * rr * nw[d ^ 64];
        const float c = cosb[srow * HD + d];
        const float s = sinb[srow * HD + d];
        const float ov = hi2 ? (nv * c + nvp * s) : (nv * c - nvp * s);
        o8[e] = (_Float16)(ov * scale);
      }
      *(f16x8*)(dst + base + hi2 * 64 + jv * 8) = o8;
    }
  } else {
    const int kvh = slot - 40;
    const int d = w * 32 + (lane >> 1);
    const int sh = lane & 1;
    const long vb = (long)kvh * HD * SLEN + (long)d * SLEN + row0 + sh * 64;
#pragma unroll
    for (int jv = 0; jv < 8; ++jv) {
      short8 o8;
#pragma unroll
      for (int e = 0; e < 8; ++e) {
        const bf16 hv = __float2bfloat16(T[(sh * 64 + jv * 8 + e) * 133 + d]);
        short sb;
        __builtin_memcpy(&sb, &hv, 2);
        o8[e] = sb;
      }
      *(short8*)(Vt + vb + jv * 8) = o8;
    }
  }
}

// dst[z][n][k] = bf16(src[z][k][n]), fp32 src. 64x64 tiles via LDS, 4B stores.
__global__ __launch_bounds__(256) void transpose_kernel(
    const float* __restrict__ src, long srcZ, int srcLd,
    bf16* __restrict__ dst, long dstZ, int dstLd)
{
  __shared__ float t[64][65];
  const int z = blockIdx.z;
  src += (long)z * srcZ;
  const long db = (long)z * dstZ;
  const int k0 = blockIdx.x * 64;
  const int n0 = blockIdx.y * 64;
  const int tx = threadIdx.x & 63;
  const int ty = threadIdx.x >> 6;
#pragma unroll
  for (int r = ty; r < 64; r += 4)
    t[r][tx] = src[(long)(k0 + r) * srcLd + n0 + tx];
  __syncthreads();
  const int tx2 = threadIdx.x & 31;
  const int ty2 = threadIdx.x >> 5;
#pragma unroll
  for (int r = ty2; r < 64; r += 8) {
    const unsigned int pr = cvtpk(t[2 * tx2][r], t[2 * tx2 + 1][r]);
    *(unsigned int*)(dst + db + (long)(n0 + r) * dstLd + k0 + 2 * tx2) = pr;
  }
}

__global__ __launch_bounds__(256) void cvt_bf16_kernel(
    const float* __restrict__ x, bf16* __restrict__ y, int n)
{
  const int i = (blockIdx.x * 256 + threadIdx.x) * 4;
  if (i >= n) return;
  const f32x4 v = *(const f32x4*)(x + i);
#pragma unroll
  for (int j = 0; j < 4; ++j) y[i + j] = __float2bfloat16(v[j]);
}

// Flash v9: v7 numerics (no-max 2^s softmax, ones-MFMA row sums) with
// single-buffered V -> LDS 48 KB -> 3 blocks/CU (12 waves, 3/SIMD).
// Ledger: tail(t) = {barrier; issue V(t+1)+K(t+2); vmcnt(8)->K(t+1) landed;
// barrier}; mid(t) = {vmcnt(4)->V(t) landed; barrier; PV}. Never drains to 0.
__global__ __launch_bounds__(256, 3) void flash_kernel(
    const _Float16* __restrict__ qf, const _Float16* __restrict__ kf,
    const bf16* __restrict__ vt,   // [kvh][d=128][s=2048]
    bf16* __restrict__ AO)         // [2048][4096]
{
  __shared__ __align__(16) _Float16 sK[2][64 * 128];  // 32 KB
  __shared__ __align__(16) bf16 sV[64 * 128];         // 16 KB (single buffer)

  const int lin = blockIdx.x;
  const int swz = (lin & 7) * 64 + (lin >> 3);
  const int head = swz >> 4;
  const int qt = swz & 15;
  const int kvh = head >> 2;

  const int tid = threadIdx.x;
  const int w = tid >> 6;
  const int lane = tid & 63;
  const int q31 = lane & 31;
  const int hi = lane >> 5;

  f16x8 bq[8];
  {
    const long qb = ((long)head * SLEN + qt * 128 + w * 32 + q31) * HD + hi * 8;
#pragma unroll
    for (int ks = 0; ks < 8; ++ks)
      bq[ks] = *(const f16x8*)(qf + qb + ks * 16);
  }

  short8 ones;
#pragma unroll
  for (int e = 0; e < 8; ++e) ones[e] = (short)0x3F80;  // bf16 1.0

  const _Float16* kb = kf + (long)kvh * SLEN * HD;
  const bf16* vb = vt + (long)kvh * HD * SLEN;

  auto stageK = [&](int t, int buf) {
#pragma unroll
    for (int i = 0; i < 4; ++i) {
      const int c = i * 256 + tid;
      const int row = c >> 4;
      const int sg = (c & 15) ^ (row & 15);
      gld16(kb + (long)(t * 64 + row) * HD + sg * 8,
            (_Float16*)sK[buf] + (i * 256 + w * 64) * 8);
    }
  };
  auto stageV = [&](int t) {
#pragma unroll
    for (int i = 0; i < 4; ++i) {
      const int c = i * 256 + tid;
      const int rp = c >> 4;
      const int sg = (c & 15) ^ (rp & 15);
      const int d = rp * 2 + (sg >> 3);
      gld16(vb + (long)d * SLEN + t * 64 + (sg & 7) * 8,
            (bf16*)sV + (i * 256 + w * 64) * 8);
    }
  };

  f32x16 o[4] = {};
  f32x16 o4 = {};

  // prologue: K(0), V(0), K(1) in flight; K(0) landed at loop entry
  stageK(0, 0);
  stageV(0);
  stageK(1, 1);
  asm volatile("s_waitcnt vmcnt(8)" ::: "memory");
  __builtin_amdgcn_sched_barrier(0);
  __builtin_amdgcn_s_barrier();
  __builtin_amdgcn_sched_barrier(0);

  const int NT = SLEN / 64;
  for (int t = 0; t < NT; ++t) {
    const int cur = t & 1;
    const _Float16* K = sK[cur];

    // S^T[64key][32q] = mfma(K, Q); Q carries log2e
    f32x16 s0 = {}, s1 = {};
    __builtin_amdgcn_s_setprio(1);
#pragma unroll
    for (int ks = 0; ks < 8; ++ks) {
      const int slot = (2 * ks + hi) ^ (q31 & 15);
      const f16x8 a0 = *(const f16x8*)(K + q31 * 128 + slot * 8);
      const f16x8 a1 = *(const f16x8*)(K + (32 + q31) * 128 + slot * 8);
      s0 = __builtin_amdgcn_mfma_f32_32x32x16_f16(a0, bq[ks], s0, 0, 0, 0);
      s1 = __builtin_amdgcn_mfma_f32_32x32x16_f16(a1, bq[ks], s1, 0, 0, 0);
    }
    __builtin_amdgcn_s_setprio(0);

    // P = 2^s, unnormalized
#pragma unroll
    for (int r = 0; r < 16; ++r) s0[r] = exp2f(s0[r]);
#pragma unroll
    for (int r = 0; r < 16; ++r) s1[r] = exp2f(s1[r]);

    unsigned int pk[16], sw[16];
#pragma unroll
    for (int i = 0; i < 8; ++i) pk[i] = cvtpk(s0[2 * i], s0[2 * i + 1]);
#pragma unroll
    for (int i = 0; i < 8; ++i) pk[8 + i] = cvtpk(s1[2 * i], s1[2 * i + 1]);
#pragma unroll
    for (int i = 0; i < 16; ++i) sw[i] = __shfl_xor((int)pk[i], 32);

    short8 pa[4];
#pragma unroll
    for (int ks = 0; ks < 4; ++ks) {
      const int base = (ks >> 1) * 8 + (ks & 1) * 4 + 2 * hi;
      union { unsigned int u[4]; short8 v; } tu;
      if (hi == 0) {
        tu.u[0] = pk[base]; tu.u[1] = pk[base + 1];
        tu.u[2] = sw[base]; tu.u[3] = sw[base + 1];
      } else {
        tu.u[0] = sw[base]; tu.u[1] = sw[base + 1];
        tu.u[2] = pk[base]; tu.u[3] = pk[base + 1];
      }
      pa[ks] = tu.v;
    }

    // mid: V(t) landed (only K(t+1) may remain in flight)
    if (t + 1 < NT) {
      asm volatile("s_waitcnt vmcnt(4)" ::: "memory");
    } else {
      asm volatile("s_waitcnt vmcnt(0)" ::: "memory");
    }
    __builtin_amdgcn_sched_barrier(0);
    __builtin_amdgcn_s_barrier();
    __builtin_amdgcn_sched_barrier(0);

    // O += P V ; row sums via ones-MFMA
    __builtin_amdgcn_s_setprio(1);
#pragma unroll
    for (int ks = 0; ks < 4; ++ks)
      o4 = __builtin_amdgcn_mfma_f32_32x32x16_bf16(pa[ks], ones, o4, 0, 0, 0);
#pragma unroll
    for (int nt = 0; nt < 4; ++nt) {
      const int d = nt * 32 + q31;
      const int rp = d >> 1;
      const int sbase = ((d & 1) << 3) + hi;
#pragma unroll
      for (int ks = 0; ks < 4; ++ks) {
        const int slot = (sbase + 2 * ks) ^ (rp & 15);
        const short8 bv = *(const short8*)((const bf16*)sV + rp * 128 + slot * 8);
        o[nt] = __builtin_amdgcn_mfma_f32_32x32x16_bf16(pa[ks], bv, o[nt], 0, 0, 0);
      }
    }
    __builtin_amdgcn_s_setprio(0);

    // tail: refill V (single buffer) and K (double buffer)
    if (t + 1 < NT) {
      __builtin_amdgcn_s_barrier();     // all waves done reading sV / sK[cur]
      __builtin_amdgcn_sched_barrier(0);
      stageV(t + 1);
      const bool ik = (t + 2 < NT);
      if (ik) stageK(t + 2, cur);
      if (ik) { asm volatile("s_waitcnt vmcnt(8)" ::: "memory"); }
      else    { asm volatile("s_waitcnt vmcnt(4)" ::: "memory"); }
      __builtin_amdgcn_sched_barrier(0);
      __builtin_amdgcn_s_barrier();     // K(t+1) resident for all waves
      __builtin_amdgcn_sched_barrier(0);
    }
  }

  // normalize: o and o4 share the C/D row layout
  f32x16 inv;
#pragma unroll
  for (int r = 0; r < 16; ++r) inv[r] = 1.0f / o4[r];
#pragma unroll
  for (int nt = 0; nt < 4; ++nt)
#pragma unroll
    for (int rr = 0; rr < 4; ++rr)
#pragma unroll
      for (int j = 0; j < 4; ++j) {
        const long row = qt * 128 + w * 32 + 8 * rr + 4 * hi + j;
        AO[row * HIDN + head * 128 + nt * 32 + q31] =
            __float2bfloat16(o[nt][rr * 4 + j] * inv[rr * 4 + j]);
      }
}

extern "C" void kernel_launch(void* const* d_in, const int* in_sizes, int n_in,
                              void* d_out, int out_size, void* d_ws, size_t ws_size,
                              hipStream_t stream)
{
  const float* hs   = (const float*)d_in[0];
  const float* cosb = (const float*)d_in[1];
  const float* sinb = (const float*)d_in[2];
  const float* wq   = (const float*)d_in[3];
  const float* wk   = (const float*)d_in[4];
  const float* wv   = (const float*)d_in[5];
  const float* wo   = (const float*)d_in[6];
  const float* qw   = (const float*)d_in[7];
  const float* kw   = (const float*)d_in[8];
  const float* eps  = (const float*)d_in[9];

  const size_t MB = 1024 * 1024;
  if (ws_size < 116 * MB) return;  // known-good budget
  uint8_t* ws = (uint8_t*)d_ws;

  bf16*  hsb = (bf16*)(ws + 0 * MB);         // [2048][4096]       16 MiB
  bf16*  WT  = (bf16*)(ws + 16 * MB);        // [6144][4096]       48 MiB
  _Float16* qf = (_Float16*)(ws + 64 * MB);  // [32][2048][128]    16 MiB
  _Float16* kf = (_Float16*)(ws + 80 * MB);  // [8][2048][128]      4 MiB
  bf16*  Vt  = (bf16*)(ws + 84 * MB);        // [8][128][2048]      4 MiB
  bf16*  AO  = (bf16*)(ws + 88 * MB);        // [2048][4096]       16 MiB
  bf16*  WoT = (bf16*)(ws + 0 * MB);         // [4096][4096]       32 MiB (over hsb/WT)

  cvt_bf16_kernel<<<SLEN * HIDN / 4 / 256, 256, 0, stream>>>(hs, hsb, SLEN * HIDN);

  transpose_kernel<<<dim3(64, 64, 1), 256, 0, stream>>>(wq, 0, HIDN, WT, 0, HIDN);
  transpose_kernel<<<dim3(64, 16, 1), 256, 0, stream>>>(wk, 0, 1024, WT + (size_t)4096 * HIDN, 0, HIDN);
  transpose_kernel<<<dim3(64, 16, 1), 256, 0, stream>>>(wv, 0, 1024, WT + (size_t)5120 * HIDN, 0, HIDN);

  gemm_qkv_kernel<<<dim3(48, 16, 1), 256, 0, stream>>>(
      hsb, WT, qf, kf, Vt, cosb, sinb, qw, kw, eps, HIDN, HIDN, HIDN);

  transpose_kernel<<<dim3(64, 64, 1), 256, 0, stream>>>(wo, 0, HIDN, WoT, 0, HIDN);

  // flash v9: 512 blocks, 3 blocks/CU (48 KB LDS)
  flash_kernel<<<dim3(512, 1, 1), 256, 0, stream>>>(qf, kf, Vt, AO);

  gemm_pipe_kernel<<<dim3(32, 16, 1), 256, 0, stream>>>(AO, WoT, (float*)d_out, HIDN, HIDN, HIDN, HIDN);
}

// Round 20
// 385.572 us; speedup vs baseline: 2.0093x; 2.0093x over previous
//
#include <hip/hip_runtime.h>
#include <hip/hip_bf16.h>
#include <stdint.h>

#define SLEN 2048
#define HIDN 4096
#define NHEAD 32
#define NKV 8
#define HD 128
#define QKV_N 6144

typedef __hip_bfloat16 bf16;
typedef short short8 __attribute__((ext_vector_type(8)));
typedef _Float16 f16x8 __attribute__((ext_vector_type(8)));
typedef float f32x4 __attribute__((ext_vector_type(4)));
typedef float f32x16 __attribute__((ext_vector_type(16)));

__device__ __forceinline__ void gld16(const void* g, void* l) {
  __builtin_amdgcn_global_load_lds((const __attribute__((address_space(1))) void*)g,
                                   (__attribute__((address_space(3))) void*)l,
                                   16, 0, 0);
}

// packed bf16 convert: lo16 = bf16(a), hi16 = bf16(b)  [T12 recipe]
__device__ __forceinline__ unsigned int cvtpk(float a, float b) {
  unsigned int r;
  asm("v_cvt_pk_bf16_f32 %0, %1, %2" : "=v"(r) : "v"(a), "v"(b));
  return r;
}

// Pipelined bf16 GEMM (round-12 proven): C[M,N](fp32) = A[M,K] * B[N,K]^T.
__global__ __launch_bounds__(256, 2) void gemm_pipe_kernel(
    const bf16* __restrict__ A, const bf16* __restrict__ B,
    float* __restrict__ C, int K, int lda, int ldb, int ldc)
{
  __shared__ __align__(16) bf16 sA[2][128 * 64];
  __shared__ __align__(16) bf16 sB[2][128 * 64];

  const int bidlin = blockIdx.y * gridDim.x + blockIdx.x;
  const int xcd = bidlin & 7;
  const int local = bidlin >> 3;
  const int CW = gridDim.x >> 2;
  const int cx = xcd & 3, cy = xcd >> 2;
  const int bx = cx * CW + local % CW;
  const int by = cy * (gridDim.y >> 1) + local / CW;
  const int row0 = by * 128;
  const int col0 = bx * 128;

  const int tid = threadIdx.x;
  const int w = tid >> 6;
  const int lane = tid & 63;
  const int wr = w >> 1, wc = w & 1;
  const int fr = lane & 15;
  const int g = lane >> 4;

  auto stage = [&](int t, int b) {
    const int k0 = t << 6;
#pragma unroll
    for (int i = 0; i < 4; ++i) {
      const int c = i * 256 + tid;
      const int row = c >> 3;
      const int slot = (c & 7) ^ (row & 7);
      gld16(A + (long)(row0 + row) * lda + k0 + slot * 8,
            (bf16*)sA[b] + (i * 256 + w * 64) * 8);
    }
#pragma unroll
    for (int i = 0; i < 4; ++i) {
      const int c = i * 256 + tid;
      const int row = c >> 3;
      const int slot = (c & 7) ^ (row & 7);
      gld16(B + (long)(col0 + row) * ldb + k0 + slot * 8,
            (bf16*)sB[b] + (i * 256 + w * 64) * 8);
    }
  };

  f32x4 acc[4][4] = {};
  const int nk = K >> 6;

  stage(0, 0);

  for (int t = 0; t < nk; ++t) {
    const int buf = t & 1;
    __builtin_amdgcn_s_barrier();
    __builtin_amdgcn_sched_barrier(0);
    if (t + 1 < nk) {
      stage(t + 1, buf ^ 1);
      asm volatile("s_waitcnt vmcnt(8)" ::: "memory");
    } else {
      asm volatile("s_waitcnt vmcnt(0)" ::: "memory");
    }
    __builtin_amdgcn_sched_barrier(0);
    __builtin_amdgcn_s_barrier();
    __builtin_amdgcn_sched_barrier(0);

    const bf16* Ab = sA[buf];
    const bf16* Bb = sB[buf];

    short8 afr[4][2], bfr[4][2];
#pragma unroll
    for (int mf = 0; mf < 4; ++mf)
#pragma unroll
      for (int ks = 0; ks < 2; ++ks) {
        const int ra = wr * 64 + mf * 16 + fr;
        afr[mf][ks] = *(const short8*)(Ab + ra * 64 + (((ks << 2) + g) ^ (ra & 7)) * 8);
        const int rb = wc * 64 + mf * 16 + fr;
        bfr[mf][ks] = *(const short8*)(Bb + rb * 64 + (((ks << 2) + g) ^ (rb & 7)) * 8);
      }
    __builtin_amdgcn_s_setprio(1);
#pragma unroll
    for (int mf = 0; mf < 4; ++mf)
#pragma unroll
      for (int nf = 0; nf < 4; ++nf)
#pragma unroll
        for (int ks = 0; ks < 2; ++ks)
          acc[mf][nf] = __builtin_amdgcn_mfma_f32_16x16x32_bf16(
              afr[mf][ks], bfr[nf][ks], acc[mf][nf], 0, 0, 0);
    __builtin_amdgcn_s_setprio(0);
  }

  const int cr = g << 2;
#pragma unroll
  for (int mf = 0; mf < 4; ++mf)
#pragma unroll
    for (int nf = 0; nf < 4; ++nf)
#pragma unroll
      for (int r = 0; r < 4; ++r) {
        const long row = row0 + wr * 64 + mf * 16 + cr + r;
        const long col = col0 + wc * 64 + nf * 16 + fr;
        C[row * (long)ldc + col] = acc[mf][nf][r];
      }
}

// QKV GEMM with fused epilogue (round-14 proven).
__global__ __launch_bounds__(256, 2) void gemm_qkv_kernel(
    const bf16* __restrict__ A, const bf16* __restrict__ B,
    _Float16* __restrict__ qf, _Float16* __restrict__ kf,
    bf16* __restrict__ Vt,
    const float* __restrict__ cosb, const float* __restrict__ sinb,
    const float* __restrict__ qw, const float* __restrict__ kw,
    const float* __restrict__ epsp, int K, int lda, int ldb)
{
  __shared__ __align__(16) char smem[128 * 133 * 4];
  bf16* sAb = (bf16*)smem;
  bf16* sBb = (bf16*)(smem + 32768);
  float* T = (float*)smem;

  const int bidlin = blockIdx.y * gridDim.x + blockIdx.x;
  const int xcd = bidlin & 7;
  const int local = bidlin >> 3;
  const int CW = gridDim.x >> 2;
  const int cx = xcd & 3, cy = xcd >> 2;
  const int bx = cx * CW + local % CW;
  const int by = cy * (gridDim.y >> 1) + local / CW;
  const int row0 = by * 128;
  const int col0 = bx * 128;

  const int tid = threadIdx.x;
  const int w = tid >> 6;
  const int lane = tid & 63;
  const int wr = w >> 1, wc = w & 1;
  const int fr = lane & 15;
  const int g = lane >> 4;

  auto stage = [&](int t, int b) {
    const int k0 = t << 6;
#pragma unroll
    for (int i = 0; i < 4; ++i) {
      const int c = i * 256 + tid;
      const int row = c >> 3;
      const int slot = (c & 7) ^ (row & 7);
      gld16(A + (long)(row0 + row) * lda + k0 + slot * 8,
            sAb + b * 8192 + (i * 256 + w * 64) * 8);
    }
#pragma unroll
    for (int i = 0; i < 4; ++i) {
      const int c = i * 256 + tid;
      const int row = c >> 3;
      const int slot = (c & 7) ^ (row & 7);
      gld16(B + (long)(col0 + row) * ldb + k0 + slot * 8,
            sBb + b * 8192 + (i * 256 + w * 64) * 8);
    }
  };

  f32x4 acc[4][4] = {};
  const int nk = K >> 6;

  stage(0, 0);

  for (int t = 0; t < nk; ++t) {
    const int buf = t & 1;
    __builtin_amdgcn_s_barrier();
    __builtin_amdgcn_sched_barrier(0);
    if (t + 1 < nk) {
      stage(t + 1, buf ^ 1);
      asm volatile("s_waitcnt vmcnt(8)" ::: "memory");
    } else {
      asm volatile("s_waitcnt vmcnt(0)" ::: "memory");
    }
    __builtin_amdgcn_sched_barrier(0);
    __builtin_amdgcn_s_barrier();
    __builtin_amdgcn_sched_barrier(0);

    const bf16* Ab = sAb + buf * 8192;
    const bf16* Bb = sBb + buf * 8192;

    short8 afr[4][2], bfr[4][2];
#pragma unroll
    for (int mf = 0; mf < 4; ++mf)
#pragma unroll
      for (int ks = 0; ks < 2; ++ks) {
        const int ra = wr * 64 + mf * 16 + fr;
        afr[mf][ks] = *(const short8*)(Ab + ra * 64 + (((ks << 2) + g) ^ (ra & 7)) * 8);
        const int rb = wc * 64 + mf * 16 + fr;
        bfr[mf][ks] = *(const short8*)(Bb + rb * 64 + (((ks << 2) + g) ^ (rb & 7)) * 8);
      }
    __builtin_amdgcn_s_setprio(1);
#pragma unroll
    for (int mf = 0; mf < 4; ++mf)
#pragma unroll
      for (int nf = 0; nf < 4; ++nf)
#pragma unroll
        for (int ks = 0; ks < 2; ++ks)
          acc[mf][nf] = __builtin_amdgcn_mfma_f32_16x16x32_bf16(
              afr[mf][ks], bfr[nf][ks], acc[mf][nf], 0, 0, 0);
    __builtin_amdgcn_s_setprio(0);
  }

  // ---- fused epilogue ----
  __syncthreads();
#pragma unroll
  for (int mf = 0; mf < 4; ++mf)
#pragma unroll
    for (int nf = 0; nf < 4; ++nf)
#pragma unroll
      for (int r = 0; r < 4; ++r)
        T[(wr * 64 + mf * 16 + (g << 2) + r) * 133 + wc * 64 + nf * 16 + fr] =
            acc[mf][nf][r];
  __syncthreads();

  const int slot = col0 >> 7;
  if (slot < 40) {
    const int rrow = w * 32 + (lane & 31);
    const int hi2 = lane >> 5;
    const long srow = row0 + rrow;
    const float* nw = (slot < 32) ? qw : kw;
    _Float16* dst;
    long base;
    float scale;
    if (slot < 32) {
      dst = qf; base = ((long)slot * SLEN + srow) * HD;
      scale = 1.4426950408889634f;
    } else {
      dst = kf; base = ((long)(slot - 32) * SLEN + srow) * HD;
      scale = 1.0f;
    }
    float ssq = 0.0f;
#pragma unroll
    for (int j = 0; j < 64; ++j) {
      const float v = T[rrow * 133 + hi2 * 64 + j];
      ssq += v * v;
    }
    ssq += __shfl_xor(ssq, 32);
    const float rr = rsqrtf(ssq * (1.0f / 128.0f) + epsp[0]);
#pragma unroll
    for (int jv = 0; jv < 8; ++jv) {
      f16x8 o8;
#pragma unroll
      for (int e = 0; e < 8; ++e) {
        const int d = hi2 * 64 + jv * 8 + e;
        const float nv  = T[rrow * 133 + d] * rr * nw[d];
        const float nvp = T[rrow * 133 + (d ^ 64)] * rr * nw[d ^ 64];
        const float c = cosb[srow * HD + d];
        const float s = sinb[srow * HD + d];
        const float ov = hi2 ? (nv * c + nvp * s) : (nv * c - nvp * s);
        o8[e] = (_Float16)(ov * scale);
      }
      *(f16x8*)(dst + base + hi2 * 64 + jv * 8) = o8;
    }
  } else {
    const int kvh = slot - 40;
    const int d = w * 32 + (lane >> 1);
    const int sh = lane & 1;
    const long vb = (long)kvh * HD * SLEN + (long)d * SLEN + row0 + sh * 64;
#pragma unroll
    for (int jv = 0; jv < 8; ++jv) {
      short8 o8;
#pragma unroll
      for (int e = 0; e < 8; ++e) {
        const bf16 hv = __float2bfloat16(T[(sh * 64 + jv * 8 + e) * 133 + d]);
        short sb;
        __builtin_memcpy(&sb, &hv, 2);
        o8[e] = sb;
      }
      *(short8*)(Vt + vb + jv * 8) = o8;
    }
  }
}

// dst[z][n][k] = bf16(src[z][k][n]), fp32 src. 64x64 tiles via LDS, 4B stores.
__global__ __launch_bounds__(256) void transpose_kernel(
    const float* __restrict__ src, long srcZ, int srcLd,
    bf16* __restrict__ dst, long dstZ, int dstLd)
{
  __shared__ float t[64][65];
  const int z = blockIdx.z;
  src += (long)z * srcZ;
  const long db = (long)z * dstZ;
  const int k0 = blockIdx.x * 64;
  const int n0 = blockIdx.y * 64;
  const int tx = threadIdx.x & 63;
  const int ty = threadIdx.x >> 6;
#pragma unroll
  for (int r = ty; r < 64; r += 4)
    t[r][tx] = src[(long)(k0 + r) * srcLd + n0 + tx];
  __syncthreads();
  const int tx2 = threadIdx.x & 31;
  const int ty2 = threadIdx.x >> 5;
#pragma unroll
  for (int r = ty2; r < 64; r += 8) {
    const unsigned int pr = cvtpk(t[2 * tx2][r], t[2 * tx2 + 1][r]);
    *(unsigned int*)(dst + db + (long)(n0 + r) * dstLd + k0 + 2 * tx2) = pr;
  }
}

__global__ __launch_bounds__(256) void cvt_bf16_kernel(
    const float* __restrict__ x, bf16* __restrict__ y, int n)
{
  const int i = (blockIdx.x * 256 + threadIdx.x) * 4;
  if (i >= n) return;
  const f32x4 v = *(const f32x4*)(x + i);
#pragma unroll
  for (int j = 0; j < 4; ++j) y[i + j] = __float2bfloat16(v[j]);
}

// Flash v10: v9 pipeline (single-buffered V, 48 KB LDS -> 3 blocks/CU by LDS
// accounting) with launch_bounds(256, 2) so the register allocator keeps the
// full ~256-VGPR budget (round-19's (256,3) forced VGPR=84 -> 1.8 GB of
// scratch spills). Numerics identical to v7/v9 (validated).
__global__ __launch_bounds__(256, 2) void flash_kernel(
    const _Float16* __restrict__ qf, const _Float16* __restrict__ kf,
    const bf16* __restrict__ vt,   // [kvh][d=128][s=2048]
    bf16* __restrict__ AO)         // [2048][4096]
{
  __shared__ __align__(16) _Float16 sK[2][64 * 128];  // 32 KB
  __shared__ __align__(16) bf16 sV[64 * 128];         // 16 KB (single buffer)

  const int lin = blockIdx.x;
  const int swz = (lin & 7) * 64 + (lin >> 3);
  const int head = swz >> 4;
  const int qt = swz & 15;
  const int kvh = head >> 2;

  const int tid = threadIdx.x;
  const int w = tid >> 6;
  const int lane = tid & 63;
  const int q31 = lane & 31;
  const int hi = lane >> 5;

  f16x8 bq[8];
  {
    const long qb = ((long)head * SLEN + qt * 128 + w * 32 + q31) * HD + hi * 8;
#pragma unroll
    for (int ks = 0; ks < 8; ++ks)
      bq[ks] = *(const f16x8*)(qf + qb + ks * 16);
  }

  short8 ones;
#pragma unroll
  for (int e = 0; e < 8; ++e) ones[e] = (short)0x3F80;  // bf16 1.0

  const _Float16* kb = kf + (long)kvh * SLEN * HD;
  const bf16* vb = vt + (long)kvh * HD * SLEN;

  auto stageK = [&](int t, int buf) {
#pragma unroll
    for (int i = 0; i < 4; ++i) {
      const int c = i * 256 + tid;
      const int row = c >> 4;
      const int sg = (c & 15) ^ (row & 15);
      gld16(kb + (long)(t * 64 + row) * HD + sg * 8,
            (_Float16*)sK[buf] + (i * 256 + w * 64) * 8);
    }
  };
  auto stageV = [&](int t) {
#pragma unroll
    for (int i = 0; i < 4; ++i) {
      const int c = i * 256 + tid;
      const int rp = c >> 4;
      const int sg = (c & 15) ^ (rp & 15);
      const int d = rp * 2 + (sg >> 3);
      gld16(vb + (long)d * SLEN + t * 64 + (sg & 7) * 8,
            (bf16*)sV + (i * 256 + w * 64) * 8);
    }
  };

  f32x16 o[4] = {};
  f32x16 o4 = {};

  // prologue: K(0), V(0), K(1) in flight; K(0) landed at loop entry
  stageK(0, 0);
  stageV(0);
  stageK(1, 1);
  asm volatile("s_waitcnt vmcnt(8)" ::: "memory");
  __builtin_amdgcn_sched_barrier(0);
  __builtin_amdgcn_s_barrier();
  __builtin_amdgcn_sched_barrier(0);

  const int NT = SLEN / 64;
  for (int t = 0; t < NT; ++t) {
    const int cur = t & 1;
    const _Float16* K = sK[cur];

    // S^T[64key][32q] = mfma(K, Q); Q carries log2e
    f32x16 s0 = {}, s1 = {};
    __builtin_amdgcn_s_setprio(1);
#pragma unroll
    for (int ks = 0; ks < 8; ++ks) {
      const int slot = (2 * ks + hi) ^ (q31 & 15);
      const f16x8 a0 = *(const f16x8*)(K + q31 * 128 + slot * 8);
      const f16x8 a1 = *(const f16x8*)(K + (32 + q31) * 128 + slot * 8);
      s0 = __builtin_amdgcn_mfma_f32_32x32x16_f16(a0, bq[ks], s0, 0, 0, 0);
      s1 = __builtin_amdgcn_mfma_f32_32x32x16_f16(a1, bq[ks], s1, 0, 0, 0);
    }
    __builtin_amdgcn_s_setprio(0);

    // P = 2^s, unnormalized
#pragma unroll
    for (int r = 0; r < 16; ++r) s0[r] = exp2f(s0[r]);
#pragma unroll
    for (int r = 0; r < 16; ++r) s1[r] = exp2f(s1[r]);

    unsigned int pk[16], sw[16];
#pragma unroll
    for (int i = 0; i < 8; ++i) pk[i] = cvtpk(s0[2 * i], s0[2 * i + 1]);
#pragma unroll
    for (int i = 0; i < 8; ++i) pk[8 + i] = cvtpk(s1[2 * i], s1[2 * i + 1]);
#pragma unroll
    for (int i = 0; i < 16; ++i) sw[i] = __shfl_xor((int)pk[i], 32);

    short8 pa[4];
#pragma unroll
    for (int ks = 0; ks < 4; ++ks) {
      const int base = (ks >> 1) * 8 + (ks & 1) * 4 + 2 * hi;
      union { unsigned int u[4]; short8 v; } tu;
      if (hi == 0) {
        tu.u[0] = pk[base]; tu.u[1] = pk[base + 1];
        tu.u[2] = sw[base]; tu.u[3] = sw[base + 1];
      } else {
        tu.u[0] = sw[base]; tu.u[1] = sw[base + 1];
        tu.u[2] = pk[base]; tu.u[3] = pk[base + 1];
      }
      pa[ks] = tu.v;
    }

    // mid: V(t) landed (only K(t+1) may remain in flight)
    if (t + 1 < NT) {
      asm volatile("s_waitcnt vmcnt(4)" ::: "memory");
    } else {
      asm volatile("s_waitcnt vmcnt(0)" ::: "memory");
    }
    __builtin_amdgcn_sched_barrier(0);
    __builtin_amdgcn_s_barrier();
    __builtin_amdgcn_sched_barrier(0);

    // O += P V ; row sums via ones-MFMA
    __builtin_amdgcn_s_setprio(1);
#pragma unroll
    for (int ks = 0; ks < 4; ++ks)
      o4 = __builtin_amdgcn_mfma_f32_32x32x16_bf16(pa[ks], ones, o4, 0, 0, 0);
#pragma unroll
    for (int nt = 0; nt < 4; ++nt) {
      const int d = nt * 32 + q31;
      const int rp = d >> 1;
      const int sbase = ((d & 1) << 3) + hi;
#pragma unroll
      for (int ks = 0; ks < 4; ++ks) {
        const int slot = (sbase + 2 * ks) ^ (rp & 15);
        const short8 bv = *(const short8*)((const bf16*)sV + rp * 128 + slot * 8);
        o[nt] = __builtin_amdgcn_mfma_f32_32x32x16_bf16(pa[ks], bv, o[nt], 0, 0, 0);
      }
    }
    __builtin_amdgcn_s_setprio(0);

    // tail: refill V (single buffer) and K (double buffer)
    if (t + 1 < NT) {
      __builtin_amdgcn_s_barrier();     // all waves done reading sV / sK[cur]
      __builtin_amdgcn_sched_barrier(0);
      stageV(t + 1);
      const bool ik = (t + 2 < NT);
      if (ik) stageK(t + 2, cur);
      if (ik) { asm volatile("s_waitcnt vmcnt(8)" ::: "memory"); }
      else    { asm volatile("s_waitcnt vmcnt(4)" ::: "memory"); }
      __builtin_amdgcn_sched_barrier(0);
      __builtin_amdgcn_s_barrier();     // K(t+1) resident for all waves
      __builtin_amdgcn_sched_barrier(0);
    }
  }

  // normalize: o and o4 share the C/D row layout
  f32x16 inv;
#pragma unroll
  for (int r = 0; r < 16; ++r) inv[r] = 1.0f / o4[r];
#pragma unroll
  for (int nt = 0; nt < 4; ++nt)
#pragma unroll
    for (int rr = 0; rr < 4; ++rr)
#pragma unroll
      for (int j = 0; j < 4; ++j) {
        const long row = qt * 128 + w * 32 + 8 * rr + 4 * hi + j;
        AO[row * HIDN + head * 128 + nt * 32 + q31] =
            __float2bfloat16(o[nt][rr * 4 + j] * inv[rr * 4 + j]);
      }
}

extern "C" void kernel_launch(void* const* d_in, const int* in_sizes, int n_in,
                              void* d_out, int out_size, void* d_ws, size_t ws_size,
                              hipStream_t stream)
{
  const float* hs   = (const float*)d_in[0];
  const float* cosb = (const float*)d_in[1];
  const float* sinb = (const float*)d_in[2];
  const float* wq   = (const float*)d_in[3];
  const float* wk   = (const float*)d_in[4];
  const float* wv   = (const float*)d_in[5];
  const float* wo   = (const float*)d_in[6];
  const float* qw   = (const float*)d_in[7];
  const float* kw   = (const float*)d_in[8];
  const float* eps  = (const float*)d_in[9];

  const size_t MB = 1024 * 1024;
  if (ws_size < 116 * MB) return;  // known-good budget
  uint8_t* ws = (uint8_t*)d_ws;

  bf16*  hsb = (bf16*)(ws + 0 * MB);         // [2048][4096]       16 MiB
  bf16*  WT  = (bf16*)(ws + 16 * MB);        // [6144][4096]       48 MiB
  _Float16* qf = (_Float16*)(ws + 64 * MB);  // [32][2048][128]    16 MiB
  _Float16* kf = (_Float16*)(ws + 80 * MB);  // [8][2048][128]      4 MiB
  bf16*  Vt  = (bf16*)(ws + 84 * MB);        // [8][128][2048]      4 MiB
  bf16*  AO  = (bf16*)(ws + 88 * MB);        // [2048][4096]       16 MiB
  bf16*  WoT = (bf16*)(ws + 0 * MB);         // [4096][4096]       32 MiB (over hsb/WT)

  cvt_bf16_kernel<<<SLEN * HIDN / 4 / 256, 256, 0, stream>>>(hs, hsb, SLEN * HIDN);

  transpose_kernel<<<dim3(64, 64, 1), 256, 0, stream>>>(wq, 0, HIDN, WT, 0, HIDN);
  transpose_kernel<<<dim3(64, 16, 1), 256, 0, stream>>>(wk, 0, 1024, WT + (size_t)4096 * HIDN, 0, HIDN);
  transpose_kernel<<<dim3(64, 16, 1), 256, 0, stream>>>(wv, 0, 1024, WT + (size_t)5120 * HIDN, 0, HIDN);

  gemm_qkv_kernel<<<dim3(48, 16, 1), 256, 0, stream>>>(
      hsb, WT, qf, kf, Vt, cosb, sinb, qw, kw, eps, HIDN, HIDN, HIDN);

  transpose_kernel<<<dim3(64, 64, 1), 256, 0, stream>>>(wo, 0, HIDN, WoT, 0, HIDN);

  // flash v10: 512 blocks, 48 KB LDS (3 blocks/CU by LDS), full VGPR budget
  flash_kernel<<<dim3(512, 1, 1), 256, 0, stream>>>(qf, kf, Vt, AO);

  gemm_pipe_kernel<<<dim3(32, 16, 1), 256, 0, stream>>>(AO, WoT, (float*)d_out, HIDN, HIDN, HIDN, HIDN);
}